// Round 8
// baseline (99.389 us; speedup 1.0000x reference)
//
#include <hip/hip_runtime.h>

#define NBATCH 32
#define LPATH 256
#define NSEG 255
#define SIGLEN 4680       // 8 + 64 + 512 + 4096
#define PSTR 4688         // partial stride (floats), 8B-aligned
#define INV6 (1.0f/6.0f)
#define INV24 (1.0f/24.0f)

typedef float v2f __attribute__((ext_vector_type(2)));

// Per-signature LDS buffer, exchange-friendly layouts (see R7):
//  T4t2 : [ (c*4+eh)*128 + 2*l + p ]  (lane l=(a<<3)|b owns (a,b,c,2eh+p))
//  T3b  : [ x*68 + y*8 + z ]          T2: [a*8+b]   T1: [a]
struct __align__(16) CBuf {
    float T4t2[64 * 64];
    float T3b[8 * 68];
    float T2[64];
    float T1[8];
};                        // 18848 B; x4 = 75392 B

__device__ __forceinline__ void publish_sig(CBuf& B, const v2f S4v[32],
                                            const float S3[8], float S2, float a1a,
                                            int l, int a, int b) {
    #pragma unroll
    for (int ch = 0; ch < 32; ++ch)
        *(v2f*)&B.T4t2[ch * 128 + 2 * l] = S4v[ch];
    #pragma unroll
    for (int c = 0; c < 8; ++c)
        B.T3b[a * 68 + b * 8 + c] = S3[c];
    B.T2[l] = S2;
    if (b == 0) B.T1[a] = a1a;
}

__device__ __forceinline__ void absorb_sig(const CBuf& B, v2f S4v[32], float S3[8],
                                           float& S2, float& a1a, int l, int a, int b) {
    v2f t1v[4];
    #pragma unroll
    for (int h = 0; h < 4; ++h) t1v[h] = *(const v2f*)&B.T1[2 * h];
    const float t1a = B.T1[a];
    const float t1b = B.T1[b];
    const v2f S2v = S2, a1v = a1a;
    #pragma unroll
    for (int c = 0; c < 8; ++c) {
        const v2f S3cv = S3[c];
        #pragma unroll
        for (int h = 0; h < 4; ++h) {
            const v2f t2v = *(const v2f*)&B.T2[c * 8 + 2 * h];
            const v2f t3v = *(const v2f*)&B.T3b[b * 68 + c * 8 + 2 * h];
            const v2f t4v = *(const v2f*)&B.T4t2[(c * 4 + h) * 128 + 2 * l];
            v2f acc = S4v[c * 4 + h] + t4v;
            acc = __builtin_elementwise_fma(S3cv, t1v[h], acc);
            acc = __builtin_elementwise_fma(S2v, t2v, acc);
            acc = __builtin_elementwise_fma(a1v, t3v, acc);
            S4v[c * 4 + h] = acc;
        }
    }
    #pragma unroll
    for (int c = 0; c < 8; ++c)
        S3[c] += S2 * B.T1[c] + a1a * B.T2[b * 8 + c] + B.T3b[a * 68 + b * 8 + c];
    S2 += a1a * t1b + B.T2[l];
    a1a += t1a;
}

__device__ __forceinline__ void tree3(CBuf* bufs, v2f S4v[32], float S3[8],
                                      float& S2, float& a1a, int w, int l, int a, int b) {
    #pragma unroll
    for (int r = 0; r < 3; ++r) {
        const int stride = 1 << r;
        const int m = (stride << 1) - 1;
        if ((w & m) == stride)
            publish_sig(bufs[w >> (r + 1)], S4v, S3, S2, a1a, l, a, b);
        __syncthreads();
        if ((w & m) == 0)
            absorb_sig(bufs[w >> (r + 1)], S4v, S3, S2, a1a, l, a, b);
        __syncthreads();
    }
}

// 256 blocks = 32 batches x 8 chunks of 32 segments; 512 threads = 8 waves.
// Each block: scan 4 segs/wave -> tree3 -> wave0 stores partial -> fence+atomic.
// Last-arriving block per batch loads the 8 partials (wave k -> partial k),
// reruns tree3, writes the final signature. No spinning; order-independent FP.
__global__ __launch_bounds__(512) void sig_kernel(const float* __restrict__ path,
                                                  float* __restrict__ pbase,
                                                  int* __restrict__ flags,
                                                  float* __restrict__ out) {
    const int blk = blockIdx.x;
    const int n = blk >> 3, cb = blk & 7;
    const int t = threadIdx.x;
    const int w = t >> 6, l = t & 63, a = l >> 3, b = l & 7;

    __shared__ CBuf bufs[4];
    __shared__ float dbuf[256];   // this block's 32 segments x 8
    __shared__ int sh_old;

    const float* prow = path + n * (LPATH * 8);
    if (t < 64) {
        const int i4 = t * 4;
        const int g4 = cb * 256 + i4;
        if (g4 < NSEG * 8) {       // seg <= 254: real increment quad
            const float4 x0 = *(const float4*)&prow[g4];
            const float4 x1 = *(const float4*)&prow[g4 + 8];
            *(float4*)&dbuf[i4] = make_float4(x1.x - x0.x, x1.y - x0.y,
                                              x1.z - x0.z, x1.w - x0.w);
        } else {                   // seg 255: identity pad
            *(float4*)&dbuf[i4] = make_float4(0.f, 0.f, 0.f, 0.f);
        }
    }
    __syncthreads();

    v2f S4v[32];
    float S3[8];
    #pragma unroll
    for (int j = 0; j < 32; ++j) S4v[j] = (v2f)0.f;
    #pragma unroll
    for (int c = 0; c < 8; ++c) S3[c] = 0.f;
    float S2 = 0.f, a1a = 0.f;

    // ---- scan 4 segments, fully unrolled ----
    #pragma unroll
    for (int ss = 0; ss < 4; ++ss) {
        const int s = (w << 2) + ss;
        const float4 dlo = *(const float4*)&dbuf[s * 8];
        const float4 dhi = *(const float4*)&dbuf[s * 8 + 4];
        const v2f dp[4] = {{dlo.x, dlo.y}, {dlo.z, dlo.w},
                           {dhi.x, dhi.y}, {dhi.z, dhi.w}};
        const float da = dbuf[s * 8 + a];
        const float db = dbuf[s * 8 + b];
        const float dab = da * db;
        const float P = dab * INV24 + a1a * db * INV6 + S2 * 0.5f;
        const float Q = dab * INV6  + a1a * db * 0.5f + S2;
        const v2f Pv = P, Qv = Q;
        v2f Kv[4];
        #pragma unroll
        for (int h = 0; h < 4; ++h) {
            v2f S3h = {S3[2 * h], S3[2 * h + 1]};
            Kv[h] = __builtin_elementwise_fma(dp[h], Pv, S3h);
            S3h = __builtin_elementwise_fma(dp[h], Qv, S3h);
            S3[2 * h] = S3h.x; S3[2 * h + 1] = S3h.y;
        }
        #pragma unroll
        for (int c = 0; c < 8; ++c) {
            const float Kc = (c & 1) ? Kv[c >> 1].y : Kv[c >> 1].x;
            const v2f Kcv = Kc;
            #pragma unroll
            for (int h = 0; h < 4; ++h)
                S4v[c * 4 + h] = __builtin_elementwise_fma(dp[h], Kcv, S4v[c * 4 + h]);
        }
        S2 += db * (da * 0.5f + a1a);
        a1a += da;
    }

    // ---- intra-block combine ----
    tree3(bufs, S4v, S3, S2, a1a, w, l, a, b);

    // ---- wave 0 stores the block partial (coalesced, transposed S4) ----
    if (w == 0) {
        float* p = pbase + (size_t)blk * PSTR;
        if (b == 0) p[a] = a1a;
        p[8 + l] = S2;
        #pragma unroll
        for (int c = 0; c < 8; ++c) p[72 + c * 64 + l] = S3[c];
        #pragma unroll
        for (int ch = 0; ch < 32; ++ch)
            *(v2f*)&p[584 + ch * 128 + 2 * l] = S4v[ch];
    }

    // ---- release partial, count arrivals ----
    __threadfence();
    __syncthreads();
    if (t == 0)
        sh_old = __hip_atomic_fetch_add(&flags[n], 1, __ATOMIC_ACQ_REL,
                                        __HIP_MEMORY_SCOPE_AGENT);
    __syncthreads();
    if (sh_old != 7) return;      // not the last block of this batch

    // ---- combiner: acquire, load the 8 partials (wave k -> partial k) ----
    __threadfence();
    {
        const float* p = pbase + (size_t)(n * 8 + w) * PSTR;
        a1a = p[a];
        S2 = p[8 + l];
        #pragma unroll
        for (int c = 0; c < 8; ++c) S3[c] = p[72 + c * 64 + l];
        #pragma unroll
        for (int ch = 0; ch < 32; ++ch)
            S4v[ch] = *(const v2f*)&p[584 + ch * 128 + 2 * l];
    }
    __syncthreads();

    tree3(bufs, S4v, S3, S2, a1a, w, l, a, b);

    // ---- wave 0 writes the final signature ----
    if (w == 0) {
        float* o = out + n * SIGLEN;
        if (b == 0) o[a] = a1a;
        o[8 + l] = S2;
        *(float4*)&o[72 + l * 8]     = make_float4(S3[0], S3[1], S3[2], S3[3]);
        *(float4*)&o[72 + l * 8 + 4] = make_float4(S3[4], S3[5], S3[6], S3[7]);
        #pragma unroll
        for (int ch = 0; ch < 32; ++ch)
            *(v2f*)&o[584 + l * 64 + 2 * ch] = S4v[ch];   // (a,b,c,e) order
    }
}

extern "C" void kernel_launch(void* const* d_in, const int* in_sizes, int n_in,
                              void* d_out, int out_size, void* d_ws, size_t ws_size,
                              hipStream_t stream) {
    const float* path = (const float*)d_in[0];
    float* out = (float*)d_out;
    int* flags = (int*)d_ws;                      // 32 ints
    float* pbase = (float*)d_ws + 256;            // partials, 1 KB offset
    hipMemsetAsync(d_ws, 0, NBATCH * sizeof(int), stream);
    sig_kernel<<<NBATCH * 8, 512, 0, stream>>>(path, pbase, flags, out);
}

// Round 9
// 17.953 us; speedup vs baseline: 5.5360x; 5.5360x over previous
//
#include <hip/hip_runtime.h>

#define NBATCH 32
#define LPATH 256
#define NSEG 255
#define SIGLEN 4680       // 8 + 64 + 512 + 4096
#define INV6 (1.0f/6.0f)
#define INV24 (1.0f/24.0f)

typedef float v2f __attribute__((ext_vector_type(2)));

// Per-signature LDS buffer, exchange-friendly layouts:
//  T4t2 : level-4, e-pairs contiguous per lane: [ (c*4+eh)*128 + 2*l + p ]
//  T3b  : level-3 padded [ x*68 + y*8 + z ]
//  T2   : [ a*8+b ]    T1 : [ a ]
struct __align__(16) CBuf {
    float T4t2[64 * 64];  // 16384 B
    float T3b[8 * 68];    //  2176 B
    float T2[64];         //   256 B
    float T1[8];          //    32 B
};                        // 18848 B; x4 = 75392 B

__device__ __forceinline__ void publish_sig(CBuf& B, const v2f S4v[32],
                                            const float S3[8], float S2, float a1a,
                                            int l, int a, int b) {
    #pragma unroll
    for (int ch = 0; ch < 32; ++ch)
        *(v2f*)&B.T4t2[ch * 128 + 2 * l] = S4v[ch];
    #pragma unroll
    for (int c = 0; c < 8; ++c)
        B.T3b[a * 68 + b * 8 + c] = S3[c];
    B.T2[l] = S2;
    if (b == 0) B.T1[a] = a1a;
}

__device__ __forceinline__ void absorb_sig(const CBuf& B, v2f S4v[32], float S3[8],
                                           float& S2, float& a1a, int l, int a, int b) {
    v2f t1v[4];
    #pragma unroll
    for (int h = 0; h < 4; ++h) t1v[h] = *(const v2f*)&B.T1[2 * h];
    const float t1a = B.T1[a];
    const float t1b = B.T1[b];
    const v2f S2v = S2, a1v = a1a;
    #pragma unroll
    for (int c = 0; c < 8; ++c) {
        const v2f S3cv = S3[c];
        #pragma unroll
        for (int h = 0; h < 4; ++h) {
            const v2f t2v = *(const v2f*)&B.T2[c * 8 + 2 * h];
            const v2f t3v = *(const v2f*)&B.T3b[b * 68 + c * 8 + 2 * h];
            const v2f t4v = *(const v2f*)&B.T4t2[(c * 4 + h) * 128 + 2 * l];
            v2f acc = S4v[c * 4 + h] + t4v;
            acc = __builtin_elementwise_fma(S3cv, t1v[h], acc);
            acc = __builtin_elementwise_fma(S2v, t2v, acc);
            acc = __builtin_elementwise_fma(a1v, t3v, acc);
            S4v[c * 4 + h] = acc;
        }
    }
    #pragma unroll
    for (int c = 0; c < 8; ++c)
        S3[c] += S2 * B.T1[c] + a1a * B.T2[b * 8 + c] + B.T3b[a * 68 + b * 8 + c];
    S2 += a1a * t1b + B.T2[l];
    a1a += t1a;
}

// One block per batch; 512 threads = 8 waves. Wave w scans segments
// [32w,32w+32) (seg 255 zero-padded == identity) from LDS increments
// (fully unrolled: all ds_reads are base + compile-time offset),
// then 3-round wave-pair tree; wave 0 writes the signature.
__global__ __launch_bounds__(512, 2) void sig_kernel(const float* __restrict__ path,
                                                     float* __restrict__ out) {
    const int n = blockIdx.x;
    const int t = threadIdx.x;
    const int w = t >> 6, l = t & 63, a = l >> 3, b = l & 7;

    __shared__ CBuf bufs[4];
    __shared__ float dbuf[2048];   // 256 segs x 8 (seg 255 = 0 pad)

    const float* prow = path + n * (LPATH * 8);
    {
        const int i4 = t * 4;
        if (i4 < NSEG * 8) {       // i4 <= 2036: full diff quad (reads up to 2047)
            const float4 x0 = *(const float4*)&prow[i4];
            const float4 x1 = *(const float4*)&prow[i4 + 8];
            *(float4*)&dbuf[i4] = make_float4(x1.x - x0.x, x1.y - x0.y,
                                              x1.z - x0.z, x1.w - x0.w);
        } else {                   // i4 = 2040, 2044: pad segment 255
            *(float4*)&dbuf[i4] = make_float4(0.f, 0.f, 0.f, 0.f);
        }
    }
    __syncthreads();

    v2f S4v[32];
    float S3[8];
    #pragma unroll
    for (int j = 0; j < 32; ++j) S4v[j] = (v2f)0.f;
    #pragma unroll
    for (int c = 0; c < 8; ++c) S3[c] = 0.f;
    float S2 = 0.f, a1a = 0.f;

    // per-wave / per-lane LDS bases, computed once
    const float* wbase = &dbuf[w << 8];        // wave's 32 segments
    const float* abase = wbase + a;            // + lane's a channel
    const float* bbase = wbase + b;            // + lane's b channel

    // ---- scan 32 segments, FULLY unrolled: ds_read base+imm offsets ----
    #pragma unroll
    for (int ss = 0; ss < 32; ++ss) {
        const float4 dlo = *(const float4*)&wbase[ss * 8];
        const float4 dhi = *(const float4*)&wbase[ss * 8 + 4];
        const v2f dp[4] = {{dlo.x, dlo.y}, {dlo.z, dlo.w},
                           {dhi.x, dhi.y}, {dhi.z, dhi.w}};
        const float da = abase[ss * 8];
        const float db = bbase[ss * 8];
        const float dab = da * db;
        const float P = dab * INV24 + a1a * db * INV6 + S2 * 0.5f;
        const float Q = dab * INV6  + a1a * db * 0.5f + S2;
        const v2f Pv = P, Qv = Q;
        // K[c-pair] = d[c-pair]*P + oldS3[c-pair]; S3 += d*Q
        v2f Kv[4];
        #pragma unroll
        for (int h = 0; h < 4; ++h) {
            v2f S3h = {S3[2 * h], S3[2 * h + 1]};
            Kv[h] = __builtin_elementwise_fma(dp[h], Pv, S3h);
            S3h = __builtin_elementwise_fma(dp[h], Qv, S3h);
            S3[2 * h] = S3h.x; S3[2 * h + 1] = S3h.y;
        }
        // S4[c][e-pair] += d[e-pair] * K[c]
        #pragma unroll
        for (int c = 0; c < 8; ++c) {
            const float Kc = (c & 1) ? Kv[c >> 1].y : Kv[c >> 1].x;
            const v2f Kcv = Kc;
            #pragma unroll
            for (int h = 0; h < 4; ++h)
                S4v[c * 4 + h] = __builtin_elementwise_fma(dp[h], Kcv, S4v[c * 4 + h]);
        }
        S2 += db * (da * 0.5f + a1a);
        a1a += da;
    }

    // ---- 3-round wave-pair tree; wave 0 ends with the full signature ----
    #pragma unroll
    for (int r = 0; r < 3; ++r) {
        const int stride = 1 << r;
        const int m = (stride << 1) - 1;
        if ((w & m) == stride)
            publish_sig(bufs[w >> (r + 1)], S4v, S3, S2, a1a, l, a, b);
        __syncthreads();
        if ((w & m) == 0)
            absorb_sig(bufs[w >> (r + 1)], S4v, S3, S2, a1a, l, a, b);
        __syncthreads();
    }

    // ---- wave 0 writes [S1|S2|S3|S4] ----
    if (w == 0) {
        float* o = out + n * SIGLEN;
        if (b == 0) o[a] = a1a;
        o[8 + l] = S2;
        *(float4*)&o[72 + l * 8]     = make_float4(S3[0], S3[1], S3[2], S3[3]);
        *(float4*)&o[72 + l * 8 + 4] = make_float4(S3[4], S3[5], S3[6], S3[7]);
        #pragma unroll
        for (int ch = 0; ch < 32; ++ch)
            *(v2f*)&o[584 + l * 64 + 2 * ch] = S4v[ch];   // c*8+2h+p ordering
    }
}

extern "C" void kernel_launch(void* const* d_in, const int* in_sizes, int n_in,
                              void* d_out, int out_size, void* d_ws, size_t ws_size,
                              hipStream_t stream) {
    const float* path = (const float*)d_in[0];
    float* out = (float*)d_out;
    sig_kernel<<<NBATCH, 512, 0, stream>>>(path, out);
}